// Round 1
// baseline (1503.466 us; speedup 1.0000x reference)
//
#include <hip/hip_runtime.h>
#include <hip/hip_cooperative_groups.h>

namespace cg = cooperative_groups;

// ---------------------------------------------------------------------------
// Algebraic collapse: the scan is linear & batch-independent.
//   m_{t+1} = A m_t + beta,  A[(j,e),(i,d)] = gate[i,j]*W[i,j,e,d]
//   out = inp @ Weff^T + beff,  Weff = Wpost * S * Wpre,
//   S = (A^10)[block15, block0],  c = (sum_{k<10} A^k beta)[block15]
// Round 3: single cooperative mega-kernel (phase 0 builds + 9 steps with
// internal split-K reduce + tail chain), grid-synced; split-K widened to 8
// (512 blocks = 2/CU = 6 waves/CU) to hide direct-global fragment-load
// latency; t=9 reduce emits S/c in fp32 directly. Only final_gemm remains a
// separate launch. 27 dispatches -> 2.
// ---------------------------------------------------------------------------

typedef __bf16 bf16x8 __attribute__((ext_vector_type(8)));
typedef float f32x4 __attribute__((ext_vector_type(4)));

__device__ __forceinline__ unsigned short f2bf(float x) {
  unsigned int u = __float_as_uint(x);
  u += 0x7FFFu + ((u >> 16) & 1u);   // round-to-nearest-even
  return (unsigned short)(u >> 16);
}
__device__ __forceinline__ float bf2f(unsigned short s) {
  return __uint_as_float(((unsigned int)s) << 16);
}
__device__ __forceinline__ bf16x8 ldg8(const unsigned short* p) {
  return __builtin_bit_cast(bf16x8, *(const uint4*)p);
}
__device__ __forceinline__ f32x4 mfma16(bf16x8 a, bf16x8 b, f32x4 c) {
  return __builtin_amdgcn_mfma_f32_16x16x32_bf16(a, b, c, 0, 0, 0);
}

#define ND 2048   // num*dim
#define MT 144    // padded iterate rows (129 used: 128 propagator + 1 bias)
#define KS 8      // split-K chunks (256 k each)
#define NVB 512   // virtual step blocks: 64 n-tiles x 8 k-chunks
#define TPB 192   // 3 waves

struct CArgs {
  const float *W, *life, *bl, *inp, *bpre, *Wpre, *Wpost, *bpost;
  unsigned short *Ahi, *Alo, *QAhi, *QAlo, *QBhi, *QBlo;
  float *beta, *P, *S, *gv, *T1, *beff;
  unsigned short *Whi, *Wlo, *Ihi, *Ilo;
};

__global__ __launch_bounds__(TPB, 2) void coop_all(CArgs a) {
  cg::grid_group gg = cg::this_grid();
  const int tid = blockIdx.x * TPB + threadIdx.x;
  const int NT = gridDim.x * TPB;

  // ---------------- Phase 0: independent builds ----------------
  // 0a: A_hi/A_lo [2048x2048] row-major (n=(j,e), k=(i,d))
  for (int item = tid; item < (ND * ND) / 8; item += NT) {
    int base = item * 8;
    int n = base >> 11, k = base & 2047;
    int j = n >> 7, i = k >> 7;
    float gval = a.life[i * 16 + j];
    float gate = gval > 0.f ? gval : 0.f;
    const float* src = a.W + ((i * 16 + j) * 16384 + (n & 127) * 128 + (k & 127));
    float4 x = *(const float4*)src, y = *(const float4*)(src + 4);
    float vals[8] = {x.x, x.y, x.z, x.w, y.x, y.y, y.z, y.w};
    union { unsigned short u[8]; uint4 v; } ph, pl;
#pragma unroll
    for (int q = 0; q < 8; ++q) {
      float v = gate * vals[q];
      unsigned short h = f2bf(v);
      ph.u[q] = h;
      pl.u[q] = f2bf(v - bf2f(h));
    }
    *(uint4*)(a.Ahi + base) = ph.v;
    *(uint4*)(a.Alo + base) = pl.v;
  }
  // 0b: Q1 (t=1 iterate, exact) built directly from W; row 128 = beta; rest 0.
  //     Q1[c=d][n=(j,e)] = gate[0,j]*W[0,j,e,d]
  for (int item = tid; item < MT * ND; item += NT) {
    int m = item >> 11, n = item & 2047;
    int j = n >> 7, e = n & 127;
    unsigned short hh = 0, ll = 0;
    if (m < 128) {
      float gval = a.life[j];                       // i = 0
      float gate = gval > 0.f ? gval : 0.f;
      float v = gate * a.W[j * 16384 + e * 128 + m];
      hh = f2bf(v); ll = f2bf(v - bf2f(hh));
    } else if (m == 128) {
      float s = 0.f;
#pragma unroll
      for (int i = 0; i < 16; ++i) {
        float gval = a.life[i * 16 + j];
        float gate = gval > 0.f ? gval : 0.f;
        s += gate * a.bl[(i * 16 + j) * 128 + e];
      }
      a.beta[n] = s;
      hh = f2bf(s); ll = f2bf(s - bf2f(hh));
    }
    a.QAhi[item] = hh;
    a.QAlo[item] = ll;
  }
  // 0c: split inp -> hi/lo bf16
  for (int item = tid; item < (4096 * 512) / 8; item += NT) {
    int base = item * 8;
    float4 x = *(const float4*)(a.inp + base), y = *(const float4*)(a.inp + base + 4);
    float vals[8] = {x.x, x.y, x.z, x.w, y.x, y.y, y.z, y.w};
    union { unsigned short u[8]; uint4 v; } ph, pl;
#pragma unroll
    for (int q = 0; q < 8; ++q) {
      unsigned short h = f2bf(vals[q]);
      ph.u[q] = h;
      pl.u[q] = f2bf(vals[q] - bf2f(h));
    }
    *(uint4*)(a.Ihi + base) = ph.v;
    *(uint4*)(a.Ilo + base) = pl.v;
  }
  gg.sync();

  // ---------------- Steps t=2..10 (9 multiplies) ----------------
  const unsigned short *qh = a.QAhi, *ql = a.QAlo;
  unsigned short *oh = a.QBhi, *ol = a.QBlo;

  const int wv = threadIdx.x >> 6, lane = threadIdx.x & 63;
  const int r16 = lane & 15, q4 = lane >> 4;
  const int PSTR = MT * ND;

#pragma unroll 1
  for (int t = 1; t <= 9; ++t) {
    const bool last = (t == 9);
    // compute: P[kc][c][n] = sum_{k in chunk} QT[c,k]*A[n,k], barrier-free
#pragma unroll 1
    for (int vb = blockIdx.x; vb < NVB; vb += gridDim.x) {
      int nb = vb & 63, kc = vb >> 6;
      if (last && nb < 60) continue;               // only block-15 cols needed
      const int kbase = kc * 256 + q4 * 8;
      const int n0 = nb * 32;
      const unsigned short* pB0h = a.Ahi + (n0 + r16) * ND + kbase;
      const unsigned short* pB0l = a.Alo + (n0 + r16) * ND + kbase;
      const unsigned short* pB1h = pB0h + 16 * ND;
      const unsigned short* pB1l = pB0l + 16 * ND;
      const int m0 = wv * 48 + r16;
      const unsigned short* pA0h = qh + m0 * ND + kbase;
      const unsigned short* pA0l = ql + m0 * ND + kbase;

      f32x4 acc[3][2];
#pragma unroll
      for (int mt = 0; mt < 3; ++mt)
#pragma unroll
        for (int nt = 0; nt < 2; ++nt) acc[mt][nt] = (f32x4){0.f, 0.f, 0.f, 0.f};

#pragma unroll 2
      for (int it = 0; it < 8; ++it) {
        const int ko = it * 32;
        bf16x8 b0h = ldg8(pB0h + ko), b0l = ldg8(pB0l + ko);
        bf16x8 b1h = ldg8(pB1h + ko), b1l = ldg8(pB1l + ko);
        bf16x8 a0h = ldg8(pA0h + ko), a0l = ldg8(pA0l + ko);
        bf16x8 a1h = ldg8(pA0h + 16 * ND + ko), a1l = ldg8(pA0l + 16 * ND + ko);
        bf16x8 a2h = ldg8(pA0h + 32 * ND + ko), a2l = ldg8(pA0l + 32 * ND + ko);

        acc[0][0] = mfma16(a0h, b0h, acc[0][0]);
        acc[0][0] = mfma16(a0l, b0h, acc[0][0]);
        acc[0][0] = mfma16(a0h, b0l, acc[0][0]);
        acc[1][0] = mfma16(a1h, b0h, acc[1][0]);
        acc[1][0] = mfma16(a1l, b0h, acc[1][0]);
        acc[1][0] = mfma16(a1h, b0l, acc[1][0]);
        acc[2][0] = mfma16(a2h, b0h, acc[2][0]);
        acc[2][0] = mfma16(a2l, b0h, acc[2][0]);
        acc[2][0] = mfma16(a2h, b0l, acc[2][0]);
        acc[0][1] = mfma16(a0h, b1h, acc[0][1]);
        acc[0][1] = mfma16(a0l, b1h, acc[0][1]);
        acc[0][1] = mfma16(a0h, b1l, acc[0][1]);
        acc[1][1] = mfma16(a1h, b1h, acc[1][1]);
        acc[1][1] = mfma16(a1l, b1h, acc[1][1]);
        acc[1][1] = mfma16(a1h, b1l, acc[1][1]);
        acc[2][1] = mfma16(a2h, b1h, acc[2][1]);
        acc[2][1] = mfma16(a2l, b1h, acc[2][1]);
        acc[2][1] = mfma16(a2h, b1l, acc[2][1]);
      }

      float* Pk = a.P + kc * PSTR;
#pragma unroll
      for (int mt = 0; mt < 3; ++mt)
#pragma unroll
        for (int nt = 0; nt < 2; ++nt) {
          int mbase = wv * 48 + mt * 16 + q4 * 4;
          int n = n0 + nt * 16 + r16;
#pragma unroll
          for (int r = 0; r < 4; ++r)
            Pk[(mbase + r) * ND + n] = acc[mt][nt][r];
        }
    }
    gg.sync();

    // reduce
    if (!last) {
      for (int item = tid; item < (MT * ND) / 4; item += NT) {
        int m = item >> 9, c4 = item & 511;
        int n = c4 * 4;
        int idx = m * ND + n;
        float v0 = 0.f, v1 = 0.f, v2 = 0.f, v3 = 0.f;
#pragma unroll
        for (int c = 0; c < KS; ++c) {
          float4 s = *(const float4*)(a.P + c * PSTR + idx);
          v0 += s.x; v1 += s.y; v2 += s.z; v3 += s.w;
        }
        if (m == 128) {
          float4 b4 = *(const float4*)(a.beta + n);
          v0 += b4.x; v1 += b4.y; v2 += b4.z; v3 += b4.w;
        }
        union { unsigned short u[4]; uint2 d; } h, l;
        float vv[4] = {v0, v1, v2, v3};
#pragma unroll
        for (int x = 0; x < 4; ++x) {
          unsigned short hh = f2bf(vv[x]);
          h.u[x] = hh;
          l.u[x] = f2bf(vv[x] - bf2f(hh));
        }
        *(uint2*)(oh + idx) = h.d;
        *(uint2*)(ol + idx) = l.d;
      }
    } else {
      // t=9 reduce writes S[e,d] and c[e] directly in fp32 (cols 1920..2047)
      for (int item = tid; item < 129 * 32; item += NT) {
        int m = item >> 5, c4 = item & 31;
        int n = 1920 + c4 * 4;
        int idx = m * ND + n;
        float v[4] = {0.f, 0.f, 0.f, 0.f};
#pragma unroll
        for (int c = 0; c < KS; ++c) {
          float4 s = *(const float4*)(a.P + c * PSTR + idx);
          v[0] += s.x; v[1] += s.y; v[2] += s.z; v[3] += s.w;
        }
        if (m < 128) {
#pragma unroll
          for (int x = 0; x < 4; ++x) a.S[(c4 * 4 + x) * 128 + m] = v[x];
        } else {
          float4 b4 = *(const float4*)(a.beta + n);
          float bb[4] = {b4.x, b4.y, b4.z, b4.w};
#pragma unroll
          for (int x = 0; x < 4; ++x) a.gv[c4 * 4 + x] = v[x] + bb[x];
        }
      }
    }
    gg.sync();

    const unsigned short* th = qh; qh = oh; oh = (unsigned short*)th;
    const unsigned short* tl = ql; ql = ol; ol = (unsigned short*)tl;
  }

  // ---------------- Tail: T1 = S*Wpre ; g = c + S*bpre ----------------
  for (int item = tid; item < 65536 + 128; item += NT) {
    if (item < 65536) {
      int e = item >> 9, ic = item & 511;
      float s = 0.f;
      for (int d = 0; d < 128; ++d) s += a.S[e * 128 + d] * a.Wpre[d * 512 + ic];
      a.T1[item] = s;
    } else {
      int e = item - 65536;
      float s = a.gv[e];
      for (int d = 0; d < 128; ++d) s += a.S[e * 128 + d] * a.bpre[d];
      a.gv[e] = s;
    }
  }
  gg.sync();

  // ---------------- Tail: Weff = Wpost*T1 (split bf16) ; beff ----------------
  for (int item = tid; item < 262144 + 512; item += NT) {
    if (item < 262144) {
      int o = item >> 9, ic = item & 511;
      float s = 0.f;
      for (int e = 0; e < 128; ++e) s += a.Wpost[o * 128 + e] * a.T1[e * 512 + ic];
      unsigned short h = f2bf(s);
      a.Whi[item] = h;
      a.Wlo[item] = f2bf(s - bf2f(h));
    } else {
      int o = item - 262144;
      float s = a.bpost[o];
      for (int e = 0; e < 128; ++e) s += a.Wpost[o * 128 + e] * a.gv[e];
      a.beff[o] = s;
    }
  }
}

// out[4096,512] = inp @ Weff^T + beff. M=4096,N=512,K=512, split bf16.
// Block tile 64(M) x 128(N): grid (64,4), 4 waves; wave w owns n-cols [32w,32w+32).
__global__ __launch_bounds__(256) void final_gemm(
    const unsigned short* __restrict__ Ihi, const unsigned short* __restrict__ Ilo,
    const unsigned short* __restrict__ Whi, const unsigned short* __restrict__ Wlo,
    const float* __restrict__ beff, float* __restrict__ out) {
  __shared__ __align__(16) unsigned short Is_hi[64][40], Is_lo[64][40];
  __shared__ __align__(16) unsigned short Ws_hi[128][40], Ws_lo[128][40];
  const int t = threadIdx.x;
  const int mb = blockIdx.x, nb = blockIdx.y;
  const int w = t >> 6, lane = t & 63;
  const int r16 = lane & 15, q = lane >> 4;

  f32x4 acc[4][2];
#pragma unroll
  for (int x = 0; x < 4; ++x)
#pragma unroll
    for (int b = 0; b < 2; ++b) acc[x][b] = (f32x4){0.f, 0.f, 0.f, 0.f};

  for (int kc = 0; kc < 16; ++kc) {
    const int k0 = kc * 32;
#pragma unroll
    for (int rpt = 0; rpt < 6; ++rpt) {
      int slot = t + rpt * 256;
      if (slot < 512) {
        int arr = slot >> 8, s = slot & 255;
        int row = s >> 2, off = (s & 3) * 8;
        const unsigned short* src = arr ? Ilo : Ihi;
        unsigned short* dst = arr ? &Is_lo[row][off] : &Is_hi[row][off];
        *(uint4*)dst = *(const uint4*)(src + (mb * 64 + row) * 512 + k0 + off);
      } else {
        int s = slot - 512;
        int arr = s >> 9, s2 = s & 511;
        int row = s2 >> 2, off = (s2 & 3) * 8;
        const unsigned short* src = arr ? Wlo : Whi;
        unsigned short* dst = arr ? &Ws_lo[row][off] : &Ws_hi[row][off];
        *(uint4*)dst = *(const uint4*)(src + (nb * 128 + row) * 512 + k0 + off);
      }
    }
    __syncthreads();

    bf16x8 bh0 = __builtin_bit_cast(bf16x8, *(const uint4*)&Ws_hi[w * 32 + r16][q * 8]);
    bf16x8 bl0 = __builtin_bit_cast(bf16x8, *(const uint4*)&Ws_lo[w * 32 + r16][q * 8]);
    bf16x8 bh1 = __builtin_bit_cast(bf16x8, *(const uint4*)&Ws_hi[w * 32 + 16 + r16][q * 8]);
    bf16x8 bl1 = __builtin_bit_cast(bf16x8, *(const uint4*)&Ws_lo[w * 32 + 16 + r16][q * 8]);
#pragma unroll
    for (int mt = 0; mt < 4; ++mt) {
      bf16x8 ah = __builtin_bit_cast(bf16x8, *(const uint4*)&Is_hi[mt * 16 + r16][q * 8]);
      bf16x8 al = __builtin_bit_cast(bf16x8, *(const uint4*)&Is_lo[mt * 16 + r16][q * 8]);
      acc[mt][0] = mfma16(ah, bh0, acc[mt][0]);
      acc[mt][0] = mfma16(al, bh0, acc[mt][0]);
      acc[mt][0] = mfma16(ah, bl0, acc[mt][0]);
      acc[mt][1] = mfma16(ah, bh1, acc[mt][1]);
      acc[mt][1] = mfma16(al, bh1, acc[mt][1]);
      acc[mt][1] = mfma16(ah, bl1, acc[mt][1]);
    }
    __syncthreads();
  }

#pragma unroll
  for (int mt = 0; mt < 4; ++mt)
#pragma unroll
    for (int nt = 0; nt < 2; ++nt) {
      int n = nb * 128 + w * 32 + nt * 16 + r16;
      float bv = beff[n];
#pragma unroll
      for (int r = 0; r < 4; ++r) {
        int m = mb * 64 + mt * 16 + q * 4 + r;
        out[m * 512 + n] = acc[mt][nt][r] + bv;
      }
    }
}

extern "C" void kernel_launch(void* const* d_in, const int* in_sizes, int n_in,
                              void* d_out, int out_size, void* d_ws, size_t ws_size,
                              hipStream_t stream) {
  const float* inp   = (const float*)d_in[0];
  const float* Wpre  = (const float*)d_in[1];
  const float* bpre  = (const float*)d_in[2];
  const float* W     = (const float*)d_in[3];
  const float* bl    = (const float*)d_in[4];
  const float* life  = (const float*)d_in[5];
  const float* Wpost = (const float*)d_in[6];
  const float* bpost = (const float*)d_in[7];
  float* out = (float*)d_out;

  char* p = (char*)d_ws;
  auto alloc = [&](size_t bytes) {
    char* r = p;
    p += (bytes + 255) & ~(size_t)255;
    return r;
  };
  CArgs ca;
  ca.W = W; ca.life = life; ca.bl = bl; ca.inp = inp;
  ca.bpre = bpre; ca.Wpre = Wpre; ca.Wpost = Wpost; ca.bpost = bpost;
  ca.Ahi  = (unsigned short*)alloc((size_t)ND * ND * 2);
  ca.Alo  = (unsigned short*)alloc((size_t)ND * ND * 2);
  ca.QAhi = (unsigned short*)alloc((size_t)MT * ND * 2);
  ca.QAlo = (unsigned short*)alloc((size_t)MT * ND * 2);
  ca.QBhi = (unsigned short*)alloc((size_t)MT * ND * 2);
  ca.QBlo = (unsigned short*)alloc((size_t)MT * ND * 2);
  ca.beta = (float*)alloc(ND * 4);
  ca.P    = (float*)alloc((size_t)KS * MT * ND * 4);
  ca.S    = (float*)alloc(128 * 128 * 4);
  ca.gv   = (float*)alloc(128 * 4);
  ca.T1   = (float*)alloc(128 * 512 * 4);
  ca.beff = (float*)alloc(512 * 4);
  ca.Whi  = (unsigned short*)alloc(512 * 512 * 2);
  ca.Wlo  = (unsigned short*)alloc(512 * 512 * 2);
  ca.Ihi  = (unsigned short*)alloc((size_t)4096 * 512 * 2);
  ca.Ilo  = (unsigned short*)alloc((size_t)4096 * 512 * 2);

  // Clamp grid to guaranteed co-residency (phases are grid-stride safe).
  static int nblk = 0;
  if (nblk == 0) {
    int mb = 0;
    if (hipOccupancyMaxActiveBlocksPerMultiprocessor(&mb, coop_all, TPB, 0) != hipSuccess || mb < 1)
      mb = 1;
    long cap = (long)mb * 256;                      // 256 CUs on MI355X
    nblk = cap < NVB ? (int)cap : NVB;
  }

  void* kargs[] = {(void*)&ca};
  hipLaunchCooperativeKernel(coop_all, dim3(nblk), dim3(TPB), kargs, 0, stream);
  final_gemm<<<dim3(64, 4), 256, 0, stream>>>(ca.Ihi, ca.Ilo, ca.Whi, ca.Wlo, ca.beff, out);
}

// Round 2
// 428.238 us; speedup vs baseline: 3.5108x; 3.5108x over previous
//
#include <hip/hip_runtime.h>

// ---------------------------------------------------------------------------
// Algebraic collapse: the scan is linear & batch-independent.
//   m_{t+1} = A m_t + beta,  A[(j,e),(i,d)] = gate[i,j]*W[i,j,e,d]
//   out = inp @ Weff^T + beff,  Weff = Wpost * S * Wpre,
//   S = (A^10)[block15, block0],  c = (sum_{k<10} A^k beta)[block15]
// Round 4: multi-launch (cooperative grid.sync measured ~65us/sync -> dead
// end). Changes vs the 333us baseline:
//   * step split-K widened 4->8: grid (64,8)=512 blocks = 2 blocks/CU =
//     6 waves/CU (doubles latency hiding in the latency-bound step GEMM).
//   * phase-0 fused into one kernel (build_all: A, Q1+beta, inp split).
//   * tail fused into one kernel (tail_all): reduces step-9 partials to
//     S/c in fp32 directly (more accurate than bf16 round-trip) and does
//     T1/Weff/g/beff with per-block S in LDS. Kills 6 dispatches.
// Dispatches: 27 -> 20.
// ---------------------------------------------------------------------------

typedef __bf16 bf16x8 __attribute__((ext_vector_type(8)));
typedef float f32x4 __attribute__((ext_vector_type(4)));

__device__ __forceinline__ unsigned short f2bf(float x) {
  unsigned int u = __float_as_uint(x);
  u += 0x7FFFu + ((u >> 16) & 1u);   // round-to-nearest-even
  return (unsigned short)(u >> 16);
}
__device__ __forceinline__ float bf2f(unsigned short s) {
  return __uint_as_float(((unsigned int)s) << 16);
}
__device__ __forceinline__ bf16x8 ldg8(const unsigned short* p) {
  return __builtin_bit_cast(bf16x8, *(const uint4*)p);
}
__device__ __forceinline__ f32x4 mfma16(bf16x8 a, bf16x8 b, f32x4 c) {
  return __builtin_amdgcn_mfma_f32_16x16x32_bf16(a, b, c, 0, 0, 0);
}

#define ND 2048   // num*dim
#define MT 144    // padded iterate rows (129 used: 128 propagator + 1 bias)
#define KS 8      // split-K chunks (256 k each)

// ---------------------------------------------------------------------------
// Phase 0 (fused): build A hi/lo, build Q1 (t=1 iterate, exact) + beta,
// split inp -> hi/lo. All independent jobs, grid-strided.
// ---------------------------------------------------------------------------
__global__ __launch_bounds__(256) void build_all(
    const float* __restrict__ W, const float* __restrict__ life,
    const float* __restrict__ bl, const float* __restrict__ inp,
    unsigned short* __restrict__ Ahi, unsigned short* __restrict__ Alo,
    unsigned short* __restrict__ Qhi, unsigned short* __restrict__ Qlo,
    float* __restrict__ beta,
    unsigned short* __restrict__ Ihi, unsigned short* __restrict__ Ilo) {
  const int tid = blockIdx.x * 256 + threadIdx.x;
  const int NT = gridDim.x * 256;

  // Job A: A_hi/A_lo [2048x2048] row-major (n=(j,e), k=(i,d)), 8 elems/item
  for (int item = tid; item < (ND * ND) / 8; item += NT) {
    int base = item * 8;
    int n = base >> 11, k = base & 2047;
    int j = n >> 7, i = k >> 7;
    float gval = life[i * 16 + j];
    float gate = gval > 0.f ? gval : 0.f;
    const float* src = W + ((i * 16 + j) * 16384 + (n & 127) * 128 + (k & 127));
    float4 x = *(const float4*)src, y = *(const float4*)(src + 4);
    float vals[8] = {x.x, x.y, x.z, x.w, y.x, y.y, y.z, y.w};
    union { unsigned short u[8]; uint4 v; } ph, pl;
#pragma unroll
    for (int q = 0; q < 8; ++q) {
      float v = gate * vals[q];
      unsigned short h = f2bf(v);
      ph.u[q] = h;
      pl.u[q] = f2bf(v - bf2f(h));
    }
    *(uint4*)(Ahi + base) = ph.v;
    *(uint4*)(Alo + base) = pl.v;
  }

  // Job B: Q1[c=d][n=(j,e)] = gate[0,j]*W[0,j,e,d]; row 128 = beta; rest 0.
  for (int item = tid; item < MT * ND; item += NT) {
    int m = item >> 11, n = item & 2047;
    int j = n >> 7, e = n & 127;
    unsigned short hh = 0, ll = 0;
    if (m < 128) {
      float gval = life[j];                         // i = 0
      float gate = gval > 0.f ? gval : 0.f;
      float v = gate * W[j * 16384 + e * 128 + m];
      hh = f2bf(v); ll = f2bf(v - bf2f(hh));
    } else if (m == 128) {
      float s = 0.f;
#pragma unroll
      for (int i = 0; i < 16; ++i) {
        float gval = life[i * 16 + j];
        float gate = gval > 0.f ? gval : 0.f;
        s += gate * bl[(i * 16 + j) * 128 + e];
      }
      beta[n] = s;
      hh = f2bf(s); ll = f2bf(s - bf2f(hh));
    }
    Qhi[item] = hh;
    Qlo[item] = ll;
  }

  // Job C: split inp -> hi/lo bf16, 8 elems/item
  for (int item = tid; item < (4096 * 512) / 8; item += NT) {
    int base = item * 8;
    float4 x = *(const float4*)(inp + base), y = *(const float4*)(inp + base + 4);
    float vals[8] = {x.x, x.y, x.z, x.w, y.x, y.y, y.z, y.w};
    union { unsigned short u[8]; uint4 v; } ph, pl;
#pragma unroll
    for (int q = 0; q < 8; ++q) {
      unsigned short h = f2bf(vals[q]);
      ph.u[q] = h;
      pl.u[q] = f2bf(vals[q] - bf2f(h));
    }
    *(uint4*)(Ihi + base) = ph.v;
    *(uint4*)(Ilo + base) = pl.v;
  }
}

// ---------------------------------------------------------------------------
// One step, barrier-free: P[kc][c][n] = sum_{k in chunk} QT[c,k]*A[n,k].
// Grid (nb, kc): nb over 32-wide n-tiles, kc over 8 k-chunks of 256.
// Block = 3 waves; wave g owns m-rows [g*48, g*48+48) (3 m-tiles x 2 n-tiles).
// All MFMA fragments loaded directly from global, no LDS. 512 blocks = 2/CU.
// ---------------------------------------------------------------------------
__global__ __launch_bounds__(192) void step_kernel(
    const unsigned short* __restrict__ Ahi, const unsigned short* __restrict__ Alo,
    const unsigned short* __restrict__ Qhi, const unsigned short* __restrict__ Qlo,
    float* __restrict__ P, int nb_off) {
  const int t = threadIdx.x;
  const int g = t >> 6, lane = t & 63;
  const int r16 = lane & 15, q = lane >> 4;
  const int nb = blockIdx.x + nb_off;
  const int kc = blockIdx.y;
  const int kbase = kc * 256 + q * 8;
  const int n0 = nb * 32;

  const unsigned short* pB0h = Ahi + (n0 + r16) * ND + kbase;      // A rows (B-op)
  const unsigned short* pB0l = Alo + (n0 + r16) * ND + kbase;
  const unsigned short* pB1h = pB0h + 16 * ND;
  const unsigned short* pB1l = pB0l + 16 * ND;
  const int m0 = g * 48 + r16;
  const unsigned short* pA0h = Qhi + m0 * ND + kbase;              // Q rows (A-op)
  const unsigned short* pA0l = Qlo + m0 * ND + kbase;

  f32x4 acc[3][2];
#pragma unroll
  for (int mt = 0; mt < 3; ++mt)
#pragma unroll
    for (int nt = 0; nt < 2; ++nt) acc[mt][nt] = (f32x4){0.f, 0.f, 0.f, 0.f};

#pragma unroll 2
  for (int it = 0; it < 8; ++it) {
    const int ko = it * 32;
    bf16x8 b0h = ldg8(pB0h + ko), b0l = ldg8(pB0l + ko);
    bf16x8 b1h = ldg8(pB1h + ko), b1l = ldg8(pB1l + ko);
    bf16x8 a0h = ldg8(pA0h + ko), a0l = ldg8(pA0l + ko);
    bf16x8 a1h = ldg8(pA0h + 16 * ND + ko), a1l = ldg8(pA0l + 16 * ND + ko);
    bf16x8 a2h = ldg8(pA0h + 32 * ND + ko), a2l = ldg8(pA0l + 32 * ND + ko);

    acc[0][0] = mfma16(a0h, b0h, acc[0][0]);
    acc[0][0] = mfma16(a0l, b0h, acc[0][0]);
    acc[0][0] = mfma16(a0h, b0l, acc[0][0]);
    acc[1][0] = mfma16(a1h, b0h, acc[1][0]);
    acc[1][0] = mfma16(a1l, b0h, acc[1][0]);
    acc[1][0] = mfma16(a1h, b0l, acc[1][0]);
    acc[2][0] = mfma16(a2h, b0h, acc[2][0]);
    acc[2][0] = mfma16(a2l, b0h, acc[2][0]);
    acc[2][0] = mfma16(a2h, b0l, acc[2][0]);
    acc[0][1] = mfma16(a0h, b1h, acc[0][1]);
    acc[0][1] = mfma16(a0l, b1h, acc[0][1]);
    acc[0][1] = mfma16(a0h, b1l, acc[0][1]);
    acc[1][1] = mfma16(a1h, b1h, acc[1][1]);
    acc[1][1] = mfma16(a1l, b1h, acc[1][1]);
    acc[1][1] = mfma16(a1h, b1l, acc[1][1]);
    acc[2][1] = mfma16(a2h, b1h, acc[2][1]);
    acc[2][1] = mfma16(a2l, b1h, acc[2][1]);
    acc[2][1] = mfma16(a2h, b1l, acc[2][1]);
  }

  float* Pk = P + kc * (MT * ND);
#pragma unroll
  for (int mt = 0; mt < 3; ++mt)
#pragma unroll
    for (int nt = 0; nt < 2; ++nt) {
      int mbase = g * 48 + mt * 16 + q * 4;
      int n = n0 + nt * 16 + r16;
#pragma unroll
      for (int r = 0; r < 4; ++r)
        Pk[(mbase + r) * ND + n] = acc[mt][nt][r];
    }
}

// Sum KS partials, add beta on row 128, write split bf16 (full width).
__global__ __launch_bounds__(256) void reduce_step(
    const float* __restrict__ P, const float* __restrict__ beta,
    unsigned short* __restrict__ Ohi, unsigned short* __restrict__ Olo) {
  int t = blockIdx.x * 256 + threadIdx.x;   // 288*256 = 73728 = MT*ND/4
  int m = t >> 9;
  int n = (t & 511) * 4;
  int idx = m * ND + n;
  const int stride = MT * ND;
  float v0 = 0.f, v1 = 0.f, v2 = 0.f, v3 = 0.f;
#pragma unroll
  for (int c = 0; c < KS; ++c) {
    float4 s = *(const float4*)(P + c * stride + idx);
    v0 += s.x; v1 += s.y; v2 += s.z; v3 += s.w;
  }
  if (m == 128) {
    float4 b4 = *(const float4*)(beta + n);
    v0 += b4.x; v1 += b4.y; v2 += b4.z; v3 += b4.w;
  }
  union { unsigned short u[4]; uint2 d; } h, l;
  float vv[4] = {v0, v1, v2, v3};
#pragma unroll
  for (int i = 0; i < 4; ++i) {
    unsigned short hh = f2bf(vv[i]);
    h.u[i] = hh;
    l.u[i] = f2bf(vv[i] - bf2f(hh));
  }
  *(uint2*)(Ohi + idx) = h.d;
  *(uint2*)(Olo + idx) = l.d;
}

// ---------------------------------------------------------------------------
// Tail (fused): from step-9 partials P (cols 1920..2047 valid, all m rows):
//   S[e,d]   = sum_c P[c][d][1920+e]                       (fp32, exact)
//   c[e]     = sum_c P[c][128][1920+e] + beta[1920+e]
//   g[e]     = c[e] + sum_d S[e,d]*bpre[d]                 (block 0)
//   T1[e,ic] = sum_d S[e,d]*Wpre[d,ic]                     (per-block chunk)
//   Weff[o,ic] = sum_e Wpost[o,e]*T1[e,ic]  -> split bf16
//   beff[o]  = bpost[o] + sum_e Wpost[o,e]*g[e]            (block 0)
// Grid: 32 blocks x 256 thr; block b owns ic in [16b, 16b+16).
// ---------------------------------------------------------------------------
__global__ __launch_bounds__(256) void tail_all(
    const float* __restrict__ P, const float* __restrict__ beta,
    const float* __restrict__ Wpre, const float* __restrict__ bpre,
    const float* __restrict__ Wpost, const float* __restrict__ bpost,
    unsigned short* __restrict__ Whi, unsigned short* __restrict__ Wlo,
    float* __restrict__ beff) {
  __shared__ float Sl[128][129];
  __shared__ float T1l[128][17];
  __shared__ float gl[128];
  const int t = threadIdx.x;
  const int icb = blockIdx.x * 16;
  const int PSTR = MT * ND;

  // stage S (all blocks, redundant but L2/L3-hot)
  for (int s = t; s < 16384; s += 256) {
    int e = s >> 7, d = s & 127;
    float v = 0.f;
#pragma unroll
    for (int c = 0; c < KS; ++c) v += P[c * PSTR + d * ND + 1920 + e];
    Sl[e][d] = v;
  }
  __syncthreads();

  // T1 chunk; block 0 additionally computes g
  for (int s = t; s < 2048; s += 256) {
    int e = s >> 4, ics = s & 15;
    float acc = 0.f;
    for (int d = 0; d < 128; ++d) acc += Sl[e][d] * Wpre[d * 512 + icb + ics];
    T1l[e][ics] = acc;
  }
  if (blockIdx.x == 0 && t < 128) {
    int e = t;
    float cv = beta[1920 + e];
#pragma unroll
    for (int c = 0; c < KS; ++c) cv += P[c * PSTR + 128 * ND + 1920 + e];
    for (int d = 0; d < 128; ++d) cv += Sl[e][d] * bpre[d];
    gl[e] = cv;
  }
  __syncthreads();

  // Weff chunk; block 0 additionally computes beff
  const int tot = (blockIdx.x == 0) ? 8704 : 8192;
  for (int s = t; s < tot; s += 256) {
    if (s < 8192) {
      int o = s >> 4, ics = s & 15;
      float acc = 0.f;
      for (int e = 0; e < 128; ++e) acc += Wpost[o * 128 + e] * T1l[e][ics];
      unsigned short h = f2bf(acc);
      Whi[o * 512 + icb + ics] = h;
      Wlo[o * 512 + icb + ics] = f2bf(acc - bf2f(h));
    } else {
      int o = s - 8192;
      float acc = bpost[o];
      for (int e = 0; e < 128; ++e) acc += Wpost[o * 128 + e] * gl[e];
      beff[o] = acc;
    }
  }
}

// ---------------------------------------------------------------------------
// out[4096,512] = inp @ Weff^T + beff. M=4096,N=512,K=512, split bf16.
// Block tile 64(M) x 128(N): grid (64,4), 4 waves; wave w owns n-cols [32w,32w+32).
// ---------------------------------------------------------------------------
__global__ __launch_bounds__(256) void final_gemm(
    const unsigned short* __restrict__ Ihi, const unsigned short* __restrict__ Ilo,
    const unsigned short* __restrict__ Whi, const unsigned short* __restrict__ Wlo,
    const float* __restrict__ beff, float* __restrict__ out) {
  __shared__ __align__(16) unsigned short Is_hi[64][40], Is_lo[64][40];
  __shared__ __align__(16) unsigned short Ws_hi[128][40], Ws_lo[128][40];
  const int t = threadIdx.x;
  const int mb = blockIdx.x, nb = blockIdx.y;
  const int w = t >> 6, lane = t & 63;
  const int r16 = lane & 15, q = lane >> 4;

  f32x4 acc[4][2];
#pragma unroll
  for (int x = 0; x < 4; ++x)
#pragma unroll
    for (int b = 0; b < 2; ++b) acc[x][b] = (f32x4){0.f, 0.f, 0.f, 0.f};

  for (int kc = 0; kc < 16; ++kc) {
    const int k0 = kc * 32;
#pragma unroll
    for (int rpt = 0; rpt < 6; ++rpt) {
      int slot = t + rpt * 256;
      if (slot < 512) {
        int arr = slot >> 8, s = slot & 255;
        int row = s >> 2, off = (s & 3) * 8;
        const unsigned short* src = arr ? Ilo : Ihi;
        unsigned short* dst = arr ? &Is_lo[row][off] : &Is_hi[row][off];
        *(uint4*)dst = *(const uint4*)(src + (mb * 64 + row) * 512 + k0 + off);
      } else {
        int s = slot - 512;
        int arr = s >> 9, s2 = s & 511;
        int row = s2 >> 2, off = (s2 & 3) * 8;
        const unsigned short* src = arr ? Wlo : Whi;
        unsigned short* dst = arr ? &Ws_lo[row][off] : &Ws_hi[row][off];
        *(uint4*)dst = *(const uint4*)(src + (nb * 128 + row) * 512 + k0 + off);
      }
    }
    __syncthreads();

    bf16x8 bh0 = __builtin_bit_cast(bf16x8, *(const uint4*)&Ws_hi[w * 32 + r16][q * 8]);
    bf16x8 bl0 = __builtin_bit_cast(bf16x8, *(const uint4*)&Ws_lo[w * 32 + r16][q * 8]);
    bf16x8 bh1 = __builtin_bit_cast(bf16x8, *(const uint4*)&Ws_hi[w * 32 + 16 + r16][q * 8]);
    bf16x8 bl1 = __builtin_bit_cast(bf16x8, *(const uint4*)&Ws_lo[w * 32 + 16 + r16][q * 8]);
#pragma unroll
    for (int mt = 0; mt < 4; ++mt) {
      bf16x8 ah = __builtin_bit_cast(bf16x8, *(const uint4*)&Is_hi[mt * 16 + r16][q * 8]);
      bf16x8 al = __builtin_bit_cast(bf16x8, *(const uint4*)&Is_lo[mt * 16 + r16][q * 8]);
      acc[mt][0] = mfma16(ah, bh0, acc[mt][0]);
      acc[mt][0] = mfma16(al, bh0, acc[mt][0]);
      acc[mt][0] = mfma16(ah, bl0, acc[mt][0]);
      acc[mt][1] = mfma16(ah, bh1, acc[mt][1]);
      acc[mt][1] = mfma16(al, bh1, acc[mt][1]);
      acc[mt][1] = mfma16(ah, bl1, acc[mt][1]);
    }
    __syncthreads();
  }

#pragma unroll
  for (int mt = 0; mt < 4; ++mt)
#pragma unroll
    for (int nt = 0; nt < 2; ++nt) {
      int n = nb * 128 + w * 32 + nt * 16 + r16;
      float bv = beff[n];
#pragma unroll
      for (int r = 0; r < 4; ++r) {
        int m = mb * 64 + mt * 16 + q * 4 + r;
        out[m * 512 + n] = acc[mt][nt][r] + bv;
      }
    }
}

extern "C" void kernel_launch(void* const* d_in, const int* in_sizes, int n_in,
                              void* d_out, int out_size, void* d_ws, size_t ws_size,
                              hipStream_t stream) {
  const float* inp   = (const float*)d_in[0];
  const float* Wpre  = (const float*)d_in[1];
  const float* bpre  = (const float*)d_in[2];
  const float* W     = (const float*)d_in[3];
  const float* bl    = (const float*)d_in[4];
  const float* life  = (const float*)d_in[5];
  const float* Wpost = (const float*)d_in[6];
  const float* bpost = (const float*)d_in[7];
  float* out = (float*)d_out;

  char* p = (char*)d_ws;
  auto alloc = [&](size_t bytes) {
    char* r = p;
    p += (bytes + 255) & ~(size_t)255;
    return r;
  };
  unsigned short* Ahi  = (unsigned short*)alloc((size_t)ND * ND * 2);
  unsigned short* Alo  = (unsigned short*)alloc((size_t)ND * ND * 2);
  unsigned short* QAhi = (unsigned short*)alloc((size_t)MT * ND * 2);
  unsigned short* QAlo = (unsigned short*)alloc((size_t)MT * ND * 2);
  unsigned short* QBhi = (unsigned short*)alloc((size_t)MT * ND * 2);
  unsigned short* QBlo = (unsigned short*)alloc((size_t)MT * ND * 2);
  float* beta = (float*)alloc(ND * 4);
  float* P    = (float*)alloc((size_t)KS * MT * ND * 4);
  float* beff = (float*)alloc(512 * 4);
  unsigned short* Whi = (unsigned short*)alloc(512 * 512 * 2);
  unsigned short* Wlo = (unsigned short*)alloc(512 * 512 * 2);
  unsigned short* Ihi = (unsigned short*)alloc((size_t)4096 * 512 * 2);
  unsigned short* Ilo = (unsigned short*)alloc((size_t)4096 * 512 * 2);

  build_all<<<1024, 256, 0, stream>>>(W, life, bl, inp, Ahi, Alo, QAhi, QAlo,
                                      beta, Ihi, Ilo);

  // steps t=2..10: 8 full multiplies + 1 restricted to n in [1920,2048)
  const unsigned short *qh = QAhi, *ql = QAlo;
  unsigned short *oh = QBhi, *ol = QBlo;
  for (int i = 1; i <= 9; ++i) {
    if (i < 9) {
      step_kernel<<<dim3(64, KS), 192, 0, stream>>>(Ahi, Alo, qh, ql, P, 0);
      reduce_step<<<288, 256, 0, stream>>>(P, beta, oh, ol);
      const unsigned short* th = qh; qh = oh; oh = (unsigned short*)th;
      const unsigned short* tl = ql; ql = ol; ol = (unsigned short*)tl;
    } else {
      step_kernel<<<dim3(4, KS), 192, 0, stream>>>(Ahi, Alo, qh, ql, P, 60);
    }
  }

  tail_all<<<32, 256, 0, stream>>>(P, beta, Wpre, bpre, Wpost, bpost,
                                   Whi, Wlo, beff);
  final_gemm<<<dim3(64, 4), 256, 0, stream>>>(Ihi, Ilo, Whi, Wlo, beff, out);
}

// Round 3
// 322.344 us; speedup vs baseline: 4.6642x; 1.3285x over previous
//
#include <hip/hip_runtime.h>

// ---------------------------------------------------------------------------
// Algebraic collapse: the scan is linear & batch-independent.
//   m_{t+1} = A m_t + beta,  A[(j,e),(i,d)] = gate[i,j]*W[i,j,e,d]
//   out = inp @ Weff^T + beff,  Weff = Wpost * S * Wpre,
//   S = (A^10)[block15, block0],  c = (sum_{k<10} A^k beta)[block15]
// Round 5: KS 8->16 (grid (64,16)=1024 blocks = 4/CU = 12 waves/CU for the
// latency-bound step GEMM). Tail un-fused into 3 wide coalesced kernels
// (round-4's 32-block LDS-fused tail measured 167us: uncoalesced strided
// S-staging + 12.5% CU coverage). S stays fp32-exact (St[d][e] transposed
// for coalesced writes). Dispatches: 22.
// ---------------------------------------------------------------------------

typedef __bf16 bf16x8 __attribute__((ext_vector_type(8)));
typedef float f32x4 __attribute__((ext_vector_type(4)));

__device__ __forceinline__ unsigned short f2bf(float x) {
  unsigned int u = __float_as_uint(x);
  u += 0x7FFFu + ((u >> 16) & 1u);   // round-to-nearest-even
  return (unsigned short)(u >> 16);
}
__device__ __forceinline__ float bf2f(unsigned short s) {
  return __uint_as_float(((unsigned int)s) << 16);
}
__device__ __forceinline__ bf16x8 ldg8(const unsigned short* p) {
  return __builtin_bit_cast(bf16x8, *(const uint4*)p);
}
__device__ __forceinline__ f32x4 mfma16(bf16x8 a, bf16x8 b, f32x4 c) {
  return __builtin_amdgcn_mfma_f32_16x16x32_bf16(a, b, c, 0, 0, 0);
}

#define ND 2048   // num*dim
#define MT 144    // padded iterate rows (129 used: 128 propagator + 1 bias)
#define KS 16     // split-K chunks (128 k each)

// ---------------------------------------------------------------------------
// Phase 0 (fused): build A hi/lo, build Q1 (t=1 iterate, exact) + beta,
// split inp -> hi/lo. All independent jobs, grid-strided.
// ---------------------------------------------------------------------------
__global__ __launch_bounds__(256) void build_all(
    const float* __restrict__ W, const float* __restrict__ life,
    const float* __restrict__ bl, const float* __restrict__ inp,
    unsigned short* __restrict__ Ahi, unsigned short* __restrict__ Alo,
    unsigned short* __restrict__ Qhi, unsigned short* __restrict__ Qlo,
    float* __restrict__ beta,
    unsigned short* __restrict__ Ihi, unsigned short* __restrict__ Ilo) {
  const int tid = blockIdx.x * 256 + threadIdx.x;
  const int NT = gridDim.x * 256;

  // Job A: A_hi/A_lo [2048x2048] row-major (n=(j,e), k=(i,d)), 8 elems/item
  for (int item = tid; item < (ND * ND) / 8; item += NT) {
    int base = item * 8;
    int n = base >> 11, k = base & 2047;
    int j = n >> 7, i = k >> 7;
    float gval = life[i * 16 + j];
    float gate = gval > 0.f ? gval : 0.f;
    const float* src = W + ((i * 16 + j) * 16384 + (n & 127) * 128 + (k & 127));
    float4 x = *(const float4*)src, y = *(const float4*)(src + 4);
    float vals[8] = {x.x, x.y, x.z, x.w, y.x, y.y, y.z, y.w};
    union { unsigned short u[8]; uint4 v; } ph, pl;
#pragma unroll
    for (int q = 0; q < 8; ++q) {
      float v = gate * vals[q];
      unsigned short h = f2bf(v);
      ph.u[q] = h;
      pl.u[q] = f2bf(v - bf2f(h));
    }
    *(uint4*)(Ahi + base) = ph.v;
    *(uint4*)(Alo + base) = pl.v;
  }

  // Job B: Q1[c=d][n=(j,e)] = gate[0,j]*W[0,j,e,d]; row 128 = beta; rest 0.
  for (int item = tid; item < MT * ND; item += NT) {
    int m = item >> 11, n = item & 2047;
    int j = n >> 7, e = n & 127;
    unsigned short hh = 0, ll = 0;
    if (m < 128) {
      float gval = life[j];                         // i = 0
      float gate = gval > 0.f ? gval : 0.f;
      float v = gate * W[j * 16384 + e * 128 + m];
      hh = f2bf(v); ll = f2bf(v - bf2f(hh));
    } else if (m == 128) {
      float s = 0.f;
#pragma unroll
      for (int i = 0; i < 16; ++i) {
        float gval = life[i * 16 + j];
        float gate = gval > 0.f ? gval : 0.f;
        s += gate * bl[(i * 16 + j) * 128 + e];
      }
      beta[n] = s;
      hh = f2bf(s); ll = f2bf(s - bf2f(hh));
    }
    Qhi[item] = hh;
    Qlo[item] = ll;
  }

  // Job C: split inp -> hi/lo bf16, 8 elems/item
  for (int item = tid; item < (4096 * 512) / 8; item += NT) {
    int base = item * 8;
    float4 x = *(const float4*)(inp + base), y = *(const float4*)(inp + base + 4);
    float vals[8] = {x.x, x.y, x.z, x.w, y.x, y.y, y.z, y.w};
    union { unsigned short u[8]; uint4 v; } ph, pl;
#pragma unroll
    for (int q = 0; q < 8; ++q) {
      unsigned short h = f2bf(vals[q]);
      ph.u[q] = h;
      pl.u[q] = f2bf(vals[q] - bf2f(h));
    }
    *(uint4*)(Ihi + base) = ph.v;
    *(uint4*)(Ilo + base) = pl.v;
  }
}

// ---------------------------------------------------------------------------
// One step, barrier-free: P[kc][c][n] = sum_{k in chunk} QT[c,k]*A[n,k].
// Grid (nb, kc): nb over 32-wide n-tiles, kc over 16 k-chunks of 128.
// Block = 3 waves; wave g owns m-rows [g*48, g*48+48) (3 m-tiles x 2 n-tiles).
// All MFMA fragments loaded directly from global, no LDS. 1024 blocks = 4/CU.
// ---------------------------------------------------------------------------
__global__ __launch_bounds__(192) void step_kernel(
    const unsigned short* __restrict__ Ahi, const unsigned short* __restrict__ Alo,
    const unsigned short* __restrict__ Qhi, const unsigned short* __restrict__ Qlo,
    float* __restrict__ P, int nb_off) {
  const int t = threadIdx.x;
  const int g = t >> 6, lane = t & 63;
  const int r16 = lane & 15, q = lane >> 4;
  const int nb = blockIdx.x + nb_off;
  const int kc = blockIdx.y;
  const int kbase = kc * 128 + q * 8;
  const int n0 = nb * 32;

  const unsigned short* pB0h = Ahi + (n0 + r16) * ND + kbase;      // A rows (B-op)
  const unsigned short* pB0l = Alo + (n0 + r16) * ND + kbase;
  const unsigned short* pB1h = pB0h + 16 * ND;
  const unsigned short* pB1l = pB0l + 16 * ND;
  const int m0 = g * 48 + r16;
  const unsigned short* pA0h = Qhi + m0 * ND + kbase;              // Q rows (A-op)
  const unsigned short* pA0l = Qlo + m0 * ND + kbase;

  f32x4 acc[3][2];
#pragma unroll
  for (int mt = 0; mt < 3; ++mt)
#pragma unroll
    for (int nt = 0; nt < 2; ++nt) acc[mt][nt] = (f32x4){0.f, 0.f, 0.f, 0.f};

#pragma unroll
  for (int it = 0; it < 4; ++it) {
    const int ko = it * 32;
    bf16x8 b0h = ldg8(pB0h + ko), b0l = ldg8(pB0l + ko);
    bf16x8 b1h = ldg8(pB1h + ko), b1l = ldg8(pB1l + ko);
    bf16x8 a0h = ldg8(pA0h + ko), a0l = ldg8(pA0l + ko);
    bf16x8 a1h = ldg8(pA0h + 16 * ND + ko), a1l = ldg8(pA0l + 16 * ND + ko);
    bf16x8 a2h = ldg8(pA0h + 32 * ND + ko), a2l = ldg8(pA0l + 32 * ND + ko);

    acc[0][0] = mfma16(a0h, b0h, acc[0][0]);
    acc[0][0] = mfma16(a0l, b0h, acc[0][0]);
    acc[0][0] = mfma16(a0h, b0l, acc[0][0]);
    acc[1][0] = mfma16(a1h, b0h, acc[1][0]);
    acc[1][0] = mfma16(a1l, b0h, acc[1][0]);
    acc[1][0] = mfma16(a1h, b0l, acc[1][0]);
    acc[2][0] = mfma16(a2h, b0h, acc[2][0]);
    acc[2][0] = mfma16(a2l, b0h, acc[2][0]);
    acc[2][0] = mfma16(a2h, b0l, acc[2][0]);
    acc[0][1] = mfma16(a0h, b1h, acc[0][1]);
    acc[0][1] = mfma16(a0l, b1h, acc[0][1]);
    acc[0][1] = mfma16(a0h, b1l, acc[0][1]);
    acc[1][1] = mfma16(a1h, b1h, acc[1][1]);
    acc[1][1] = mfma16(a1l, b1h, acc[1][1]);
    acc[1][1] = mfma16(a1h, b1l, acc[1][1]);
    acc[2][1] = mfma16(a2h, b1h, acc[2][1]);
    acc[2][1] = mfma16(a2l, b1h, acc[2][1]);
    acc[2][1] = mfma16(a2h, b1l, acc[2][1]);
  }

  float* Pk = P + kc * (MT * ND);
#pragma unroll
  for (int mt = 0; mt < 3; ++mt)
#pragma unroll
    for (int nt = 0; nt < 2; ++nt) {
      int mbase = g * 48 + mt * 16 + q * 4;
      int n = n0 + nt * 16 + r16;
#pragma unroll
      for (int r = 0; r < 4; ++r)
        Pk[(mbase + r) * ND + n] = acc[mt][nt][r];
    }
}

// Sum KS partials, add beta on row 128, write split bf16 (full width).
__global__ __launch_bounds__(256) void reduce_step(
    const float* __restrict__ P, const float* __restrict__ beta,
    unsigned short* __restrict__ Ohi, unsigned short* __restrict__ Olo) {
  int t = blockIdx.x * 256 + threadIdx.x;   // 288*256 = 73728 = MT*ND/4
  int m = t >> 9;
  int n = (t & 511) * 4;
  int idx = m * ND + n;
  const int stride = MT * ND;
  float v0 = 0.f, v1 = 0.f, v2 = 0.f, v3 = 0.f;
#pragma unroll
  for (int c = 0; c < KS; ++c) {
    float4 s = *(const float4*)(P + c * stride + idx);
    v0 += s.x; v1 += s.y; v2 += s.z; v3 += s.w;
  }
  if (m == 128) {
    float4 b4 = *(const float4*)(beta + n);
    v0 += b4.x; v1 += b4.y; v2 += b4.z; v3 += b4.w;
  }
  union { unsigned short u[4]; uint2 d; } h, l;
  float vv[4] = {v0, v1, v2, v3};
#pragma unroll
  for (int i = 0; i < 4; ++i) {
    unsigned short hh = f2bf(vv[i]);
    h.u[i] = hh;
    l.u[i] = f2bf(vv[i] - bf2f(hh));
  }
  *(uint2*)(Ohi + idx) = h.d;
  *(uint2*)(Olo + idx) = l.d;
}

// ---------------------------------------------------------------------------
// Tail (3 wide kernels, fp32-exact S path):
//   extract_Sc: St[d][e] = sum_c P[c][d][1920+e]  (coalesced both sides);
//               c[e] = sum_c P[c][128][1920+e] + beta[1920+e]
//   tail_T1g:   T1[e,ic] = sum_d St[d][e]*Wpre[d,ic];  g[e] = c[e]+St[:,e]·bpre
//   tail_Weff:  Weff[o,ic] = sum_e Wpost[o,e]*T1[e,ic] -> split bf16;
//               beff[o] = bpost[o] + Wpost[o,:]·g
// ---------------------------------------------------------------------------
__global__ __launch_bounds__(256) void extract_Sc(
    const float* __restrict__ P, const float* __restrict__ beta,
    float* __restrict__ St, float* __restrict__ gv) {
  int t = blockIdx.x * 256 + threadIdx.x;
  const int PSTR = MT * ND;
  if (t < 16384) {
    int d = t >> 7, e = t & 127;
    float v = 0.f;
#pragma unroll
    for (int c = 0; c < KS; ++c) v += P[c * PSTR + d * ND + 1920 + e];
    St[t] = v;                                   // St[d][e]
  } else if (t < 16512) {
    int e = t - 16384;
    float v = beta[1920 + e];
#pragma unroll
    for (int c = 0; c < KS; ++c) v += P[c * PSTR + 128 * ND + 1920 + e];
    gv[e] = v;
  }
}

__global__ __launch_bounds__(256) void tail_T1g(
    const float* __restrict__ St, const float* __restrict__ Wpre,
    const float* __restrict__ bpre, float* __restrict__ T1,
    float* __restrict__ gv) {
  int t = blockIdx.x * 256 + threadIdx.x;
  if (t < 65536) {
    int e = t >> 9, ic = t & 511;
    float s = 0.f;
    for (int d = 0; d < 128; ++d) s += St[d * 128 + e] * Wpre[d * 512 + ic];
    T1[t] = s;
  } else if (t < 65664) {
    int e = t - 65536;
    float s = gv[e];
    for (int d = 0; d < 128; ++d) s += St[d * 128 + e] * bpre[d];
    gv[e] = s;                                   // only this thread touches e
  }
}

__global__ __launch_bounds__(256) void tail_Weff(
    const float* __restrict__ Wpost, const float* __restrict__ T1,
    const float* __restrict__ gv, const float* __restrict__ bpost,
    unsigned short* __restrict__ Whi, unsigned short* __restrict__ Wlo,
    float* __restrict__ beff) {
  int t = blockIdx.x * 256 + threadIdx.x;
  if (t < 262144) {
    int o = t >> 9, ic = t & 511;
    float s = 0.f;
    for (int e = 0; e < 128; ++e) s += Wpost[o * 128 + e] * T1[e * 512 + ic];
    unsigned short h = f2bf(s);
    Whi[t] = h;
    Wlo[t] = f2bf(s - bf2f(h));
  } else if (t < 262656) {
    int o = t - 262144;
    float s = bpost[o];
    for (int e = 0; e < 128; ++e) s += Wpost[o * 128 + e] * gv[e];
    beff[o] = s;
  }
}

// ---------------------------------------------------------------------------
// out[4096,512] = inp @ Weff^T + beff. M=4096,N=512,K=512, split bf16.
// Block tile 64(M) x 128(N): grid (64,4), 4 waves; wave w owns n-cols [32w,32w+32).
// ---------------------------------------------------------------------------
__global__ __launch_bounds__(256) void final_gemm(
    const unsigned short* __restrict__ Ihi, const unsigned short* __restrict__ Ilo,
    const unsigned short* __restrict__ Whi, const unsigned short* __restrict__ Wlo,
    const float* __restrict__ beff, float* __restrict__ out) {
  __shared__ __align__(16) unsigned short Is_hi[64][40], Is_lo[64][40];
  __shared__ __align__(16) unsigned short Ws_hi[128][40], Ws_lo[128][40];
  const int t = threadIdx.x;
  const int mb = blockIdx.x, nb = blockIdx.y;
  const int w = t >> 6, lane = t & 63;
  const int r16 = lane & 15, q = lane >> 4;

  f32x4 acc[4][2];
#pragma unroll
  for (int x = 0; x < 4; ++x)
#pragma unroll
    for (int b = 0; b < 2; ++b) acc[x][b] = (f32x4){0.f, 0.f, 0.f, 0.f};

  for (int kc = 0; kc < 16; ++kc) {
    const int k0 = kc * 32;
#pragma unroll
    for (int rpt = 0; rpt < 6; ++rpt) {
      int slot = t + rpt * 256;
      if (slot < 512) {
        int arr = slot >> 8, s = slot & 255;
        int row = s >> 2, off = (s & 3) * 8;
        const unsigned short* src = arr ? Ilo : Ihi;
        unsigned short* dst = arr ? &Is_lo[row][off] : &Is_hi[row][off];
        *(uint4*)dst = *(const uint4*)(src + (mb * 64 + row) * 512 + k0 + off);
      } else {
        int s = slot - 512;
        int arr = s >> 9, s2 = s & 511;
        int row = s2 >> 2, off = (s2 & 3) * 8;
        const unsigned short* src = arr ? Wlo : Whi;
        unsigned short* dst = arr ? &Ws_lo[row][off] : &Ws_hi[row][off];
        *(uint4*)dst = *(const uint4*)(src + (nb * 128 + row) * 512 + k0 + off);
      }
    }
    __syncthreads();

    bf16x8 bh0 = __builtin_bit_cast(bf16x8, *(const uint4*)&Ws_hi[w * 32 + r16][q * 8]);
    bf16x8 bl0 = __builtin_bit_cast(bf16x8, *(const uint4*)&Ws_lo[w * 32 + r16][q * 8]);
    bf16x8 bh1 = __builtin_bit_cast(bf16x8, *(const uint4*)&Ws_hi[w * 32 + 16 + r16][q * 8]);
    bf16x8 bl1 = __builtin_bit_cast(bf16x8, *(const uint4*)&Ws_lo[w * 32 + 16 + r16][q * 8]);
#pragma unroll
    for (int mt = 0; mt < 4; ++mt) {
      bf16x8 ah = __builtin_bit_cast(bf16x8, *(const uint4*)&Is_hi[mt * 16 + r16][q * 8]);
      bf16x8 al = __builtin_bit_cast(bf16x8, *(const uint4*)&Is_lo[mt * 16 + r16][q * 8]);
      acc[mt][0] = mfma16(ah, bh0, acc[mt][0]);
      acc[mt][0] = mfma16(al, bh0, acc[mt][0]);
      acc[mt][0] = mfma16(ah, bl0, acc[mt][0]);
      acc[mt][1] = mfma16(ah, bh1, acc[mt][1]);
      acc[mt][1] = mfma16(al, bh1, acc[mt][1]);
      acc[mt][1] = mfma16(ah, bl1, acc[mt][1]);
    }
    __syncthreads();
  }

#pragma unroll
  for (int mt = 0; mt < 4; ++mt)
#pragma unroll
    for (int nt = 0; nt < 2; ++nt) {
      int n = nb * 128 + w * 32 + nt * 16 + r16;
      float bv = beff[n];
#pragma unroll
      for (int r = 0; r < 4; ++r) {
        int m = mb * 64 + mt * 16 + q * 4 + r;
        out[m * 512 + n] = acc[mt][nt][r] + bv;
      }
    }
}

extern "C" void kernel_launch(void* const* d_in, const int* in_sizes, int n_in,
                              void* d_out, int out_size, void* d_ws, size_t ws_size,
                              hipStream_t stream) {
  const float* inp   = (const float*)d_in[0];
  const float* Wpre  = (const float*)d_in[1];
  const float* bpre  = (const float*)d_in[2];
  const float* W     = (const float*)d_in[3];
  const float* bl    = (const float*)d_in[4];
  const float* life  = (const float*)d_in[5];
  const float* Wpost = (const float*)d_in[6];
  const float* bpost = (const float*)d_in[7];
  float* out = (float*)d_out;

  char* p = (char*)d_ws;
  auto alloc = [&](size_t bytes) {
    char* r = p;
    p += (bytes + 255) & ~(size_t)255;
    return r;
  };
  unsigned short* Ahi  = (unsigned short*)alloc((size_t)ND * ND * 2);
  unsigned short* Alo  = (unsigned short*)alloc((size_t)ND * ND * 2);
  unsigned short* QAhi = (unsigned short*)alloc((size_t)MT * ND * 2);
  unsigned short* QAlo = (unsigned short*)alloc((size_t)MT * ND * 2);
  unsigned short* QBhi = (unsigned short*)alloc((size_t)MT * ND * 2);
  unsigned short* QBlo = (unsigned short*)alloc((size_t)MT * ND * 2);
  float* beta = (float*)alloc(ND * 4);
  float* P    = (float*)alloc((size_t)KS * MT * ND * 4);
  float* St   = (float*)alloc(128 * 128 * 4);
  float* gv   = (float*)alloc(128 * 4);
  float* T1   = (float*)alloc(128 * 512 * 4);
  float* beff = (float*)alloc(512 * 4);
  unsigned short* Whi = (unsigned short*)alloc(512 * 512 * 2);
  unsigned short* Wlo = (unsigned short*)alloc(512 * 512 * 2);
  unsigned short* Ihi = (unsigned short*)alloc((size_t)4096 * 512 * 2);
  unsigned short* Ilo = (unsigned short*)alloc((size_t)4096 * 512 * 2);

  build_all<<<1024, 256, 0, stream>>>(W, life, bl, inp, Ahi, Alo, QAhi, QAlo,
                                      beta, Ihi, Ilo);

  // steps t=2..10: 8 full multiplies + 1 restricted to n in [1920,2048)
  const unsigned short *qh = QAhi, *ql = QAlo;
  unsigned short *oh = QBhi, *ol = QBlo;
  for (int i = 1; i <= 9; ++i) {
    if (i < 9) {
      step_kernel<<<dim3(64, KS), 192, 0, stream>>>(Ahi, Alo, qh, ql, P, 0);
      reduce_step<<<288, 256, 0, stream>>>(P, beta, oh, ol);
      const unsigned short* th = qh; qh = oh; oh = (unsigned short*)th;
      const unsigned short* tl = ql; ql = ol; ol = (unsigned short*)tl;
    } else {
      step_kernel<<<dim3(4, KS), 192, 0, stream>>>(Ahi, Alo, qh, ql, P, 60);
    }
  }

  extract_Sc<<<65, 256, 0, stream>>>(P, beta, St, gv);
  tail_T1g<<<257, 256, 0, stream>>>(St, Wpre, bpre, T1, gv);
  tail_Weff<<<1026, 256, 0, stream>>>(Wpost, T1, gv, bpost, Whi, Wlo, beff);
  final_gemm<<<dim3(64, 4), 256, 0, stream>>>(Ihi, Ilo, Whi, Wlo, beff, out);
}

// Round 4
// 310.236 us; speedup vs baseline: 4.8462x; 1.0390x over previous
//
#include <hip/hip_runtime.h>

// ---------------------------------------------------------------------------
// Algebraic collapse: the scan is linear & batch-independent.
//   m_{t+1} = A m_t + beta,  A[(j,e),(i,d)] = gate[i,j]*W[i,j,e,d]
//   out = inp @ Weff^T + beff,  Weff = Wpost * S * Wpre,
//   S = (A^10)[block15, block0],  c = (sum_{k<10} A^k beta)[block15]
// Round 6: KS reverted 16->8 (KS=16 measured +50us: doubled P traffic,
// halved per-block k-amortization). Step kernel gets an explicit depth-3
// register pipeline (3 fragment sets, prefetch it+1/it+2 before MFMAs of it)
// to fix the measured VGPR=56 load-serialization. Tail stays as 3 wide
// coalesced kernels (round-5 win). Dispatches: 22.
// ---------------------------------------------------------------------------

typedef __bf16 bf16x8 __attribute__((ext_vector_type(8)));
typedef float f32x4 __attribute__((ext_vector_type(4)));

__device__ __forceinline__ unsigned short f2bf(float x) {
  unsigned int u = __float_as_uint(x);
  u += 0x7FFFu + ((u >> 16) & 1u);   // round-to-nearest-even
  return (unsigned short)(u >> 16);
}
__device__ __forceinline__ float bf2f(unsigned short s) {
  return __uint_as_float(((unsigned int)s) << 16);
}
__device__ __forceinline__ bf16x8 ldg8(const unsigned short* p) {
  return __builtin_bit_cast(bf16x8, *(const uint4*)p);
}
__device__ __forceinline__ f32x4 mfma16(bf16x8 a, bf16x8 b, f32x4 c) {
  return __builtin_amdgcn_mfma_f32_16x16x32_bf16(a, b, c, 0, 0, 0);
}

#define ND 2048   // num*dim
#define MT 144    // padded iterate rows (129 used: 128 propagator + 1 bias)
#define KS 8      // split-K chunks (256 k each)

// ---------------------------------------------------------------------------
// Phase 0 (fused): build A hi/lo, build Q1 (t=1 iterate, exact) + beta,
// split inp -> hi/lo. All independent jobs, grid-strided.
// ---------------------------------------------------------------------------
__global__ __launch_bounds__(256) void build_all(
    const float* __restrict__ W, const float* __restrict__ life,
    const float* __restrict__ bl, const float* __restrict__ inp,
    unsigned short* __restrict__ Ahi, unsigned short* __restrict__ Alo,
    unsigned short* __restrict__ Qhi, unsigned short* __restrict__ Qlo,
    float* __restrict__ beta,
    unsigned short* __restrict__ Ihi, unsigned short* __restrict__ Ilo) {
  const int tid = blockIdx.x * 256 + threadIdx.x;
  const int NT = gridDim.x * 256;

  // Job A: A_hi/A_lo [2048x2048] row-major (n=(j,e), k=(i,d)), 8 elems/item
  for (int item = tid; item < (ND * ND) / 8; item += NT) {
    int base = item * 8;
    int n = base >> 11, k = base & 2047;
    int j = n >> 7, i = k >> 7;
    float gval = life[i * 16 + j];
    float gate = gval > 0.f ? gval : 0.f;
    const float* src = W + ((i * 16 + j) * 16384 + (n & 127) * 128 + (k & 127));
    float4 x = *(const float4*)src, y = *(const float4*)(src + 4);
    float vals[8] = {x.x, x.y, x.z, x.w, y.x, y.y, y.z, y.w};
    union { unsigned short u[8]; uint4 v; } ph, pl;
#pragma unroll
    for (int q = 0; q < 8; ++q) {
      float v = gate * vals[q];
      unsigned short h = f2bf(v);
      ph.u[q] = h;
      pl.u[q] = f2bf(v - bf2f(h));
    }
    *(uint4*)(Ahi + base) = ph.v;
    *(uint4*)(Alo + base) = pl.v;
  }

  // Job B: Q1[c=d][n=(j,e)] = gate[0,j]*W[0,j,e,d]; row 128 = beta; rest 0.
  for (int item = tid; item < MT * ND; item += NT) {
    int m = item >> 11, n = item & 2047;
    int j = n >> 7, e = n & 127;
    unsigned short hh = 0, ll = 0;
    if (m < 128) {
      float gval = life[j];                         // i = 0
      float gate = gval > 0.f ? gval : 0.f;
      float v = gate * W[j * 16384 + e * 128 + m];
      hh = f2bf(v); ll = f2bf(v - bf2f(hh));
    } else if (m == 128) {
      float s = 0.f;
#pragma unroll
      for (int i = 0; i < 16; ++i) {
        float gval = life[i * 16 + j];
        float gate = gval > 0.f ? gval : 0.f;
        s += gate * bl[(i * 16 + j) * 128 + e];
      }
      beta[n] = s;
      hh = f2bf(s); ll = f2bf(s - bf2f(hh));
    }
    Qhi[item] = hh;
    Qlo[item] = ll;
  }

  // Job C: split inp -> hi/lo bf16, 8 elems/item
  for (int item = tid; item < (4096 * 512) / 8; item += NT) {
    int base = item * 8;
    float4 x = *(const float4*)(inp + base), y = *(const float4*)(inp + base + 4);
    float vals[8] = {x.x, x.y, x.z, x.w, y.x, y.y, y.z, y.w};
    union { unsigned short u[8]; uint4 v; } ph, pl;
#pragma unroll
    for (int q = 0; q < 8; ++q) {
      unsigned short h = f2bf(vals[q]);
      ph.u[q] = h;
      pl.u[q] = f2bf(vals[q] - bf2f(h));
    }
    *(uint4*)(Ihi + base) = ph.v;
    *(uint4*)(Ilo + base) = pl.v;
  }
}

// ---------------------------------------------------------------------------
// One step, barrier-free: P[kc][c][n] = sum_{k in chunk} QT[c,k]*A[n,k].
// Grid (nb, kc): nb over 32-wide n-tiles, kc over 8 k-chunks of 256.
// Block = 3 waves; wave g owns m-rows [g*48, g*48+48) (3 m-tiles x 2 n-tiles).
// Depth-3 register pipeline: 3 named fragment sets; loads for iterations
// it+1 / it+2 are in flight while MFMAs of it execute (fixes measured
// VGPR=56 load-serialization). 512 blocks = 2/CU = 6 waves/CU.
// ---------------------------------------------------------------------------
#define DECL_SET(s) \
  bf16x8 b0h##s, b0l##s, b1h##s, b1l##s, a0h##s, a0l##s, a1h##s, a1l##s, \
      a2h##s, a2l##s;

#define LOADS(s, ko)                                                         \
  b0h##s = ldg8(pB0h + (ko)); b0l##s = ldg8(pB0l + (ko));                    \
  b1h##s = ldg8(pB1h + (ko)); b1l##s = ldg8(pB1l + (ko));                    \
  a0h##s = ldg8(pA0h + (ko)); a0l##s = ldg8(pA0l + (ko));                    \
  a1h##s = ldg8(pA0h + 16 * ND + (ko)); a1l##s = ldg8(pA0l + 16 * ND + (ko)); \
  a2h##s = ldg8(pA0h + 32 * ND + (ko)); a2l##s = ldg8(pA0l + 32 * ND + (ko));

#define MFMAS(s)                                      \
  acc[0][0] = mfma16(a0h##s, b0h##s, acc[0][0]);      \
  acc[0][0] = mfma16(a0l##s, b0h##s, acc[0][0]);      \
  acc[0][0] = mfma16(a0h##s, b0l##s, acc[0][0]);      \
  acc[1][0] = mfma16(a1h##s, b0h##s, acc[1][0]);      \
  acc[1][0] = mfma16(a1l##s, b0h##s, acc[1][0]);      \
  acc[1][0] = mfma16(a1h##s, b0l##s, acc[1][0]);      \
  acc[2][0] = mfma16(a2h##s, b0h##s, acc[2][0]);      \
  acc[2][0] = mfma16(a2l##s, b0h##s, acc[2][0]);      \
  acc[2][0] = mfma16(a2h##s, b0l##s, acc[2][0]);      \
  acc[0][1] = mfma16(a0h##s, b1h##s, acc[0][1]);      \
  acc[0][1] = mfma16(a0l##s, b1h##s, acc[0][1]);      \
  acc[0][1] = mfma16(a0h##s, b1l##s, acc[0][1]);      \
  acc[1][1] = mfma16(a1h##s, b1h##s, acc[1][1]);      \
  acc[1][1] = mfma16(a1l##s, b1h##s, acc[1][1]);      \
  acc[1][1] = mfma16(a1h##s, b1l##s, acc[1][1]);      \
  acc[2][1] = mfma16(a2h##s, b1h##s, acc[2][1]);      \
  acc[2][1] = mfma16(a2l##s, b1h##s, acc[2][1]);      \
  acc[2][1] = mfma16(a2h##s, b1l##s, acc[2][1]);

__global__ __launch_bounds__(192, 2) void step_kernel(
    const unsigned short* __restrict__ Ahi, const unsigned short* __restrict__ Alo,
    const unsigned short* __restrict__ Qhi, const unsigned short* __restrict__ Qlo,
    float* __restrict__ P, int nb_off) {
  const int t = threadIdx.x;
  const int g = t >> 6, lane = t & 63;
  const int r16 = lane & 15, q = lane >> 4;
  const int nb = blockIdx.x + nb_off;
  const int kc = blockIdx.y;
  const int kbase = kc * 256 + q * 8;
  const int n0 = nb * 32;

  const unsigned short* pB0h = Ahi + (n0 + r16) * ND + kbase;      // A rows (B-op)
  const unsigned short* pB0l = Alo + (n0 + r16) * ND + kbase;
  const unsigned short* pB1h = pB0h + 16 * ND;
  const unsigned short* pB1l = pB0l + 16 * ND;
  const int m0 = g * 48 + r16;
  const unsigned short* pA0h = Qhi + m0 * ND + kbase;              // Q rows (A-op)
  const unsigned short* pA0l = Qlo + m0 * ND + kbase;

  f32x4 acc[3][2];
#pragma unroll
  for (int mt = 0; mt < 3; ++mt)
#pragma unroll
    for (int nt = 0; nt < 2; ++nt) acc[mt][nt] = (f32x4){0.f, 0.f, 0.f, 0.f};

  DECL_SET(0) DECL_SET(1) DECL_SET(2)

  // 8 k-iterations of 32, pipelined depth-3 (sets cycle 0,1,2,0,1,2,0,1)
  LOADS(0, 0)
  LOADS(1, 32)
  LOADS(2, 64)   MFMAS(0)
  LOADS(0, 96)   MFMAS(1)
  LOADS(1, 128)  MFMAS(2)
  LOADS(2, 160)  MFMAS(0)
  LOADS(0, 192)  MFMAS(1)
  LOADS(1, 224)  MFMAS(2)
  MFMAS(0)
  MFMAS(1)

  float* Pk = P + kc * (MT * ND);
#pragma unroll
  for (int mt = 0; mt < 3; ++mt)
#pragma unroll
    for (int nt = 0; nt < 2; ++nt) {
      int mbase = g * 48 + mt * 16 + q * 4;
      int n = n0 + nt * 16 + r16;
#pragma unroll
      for (int r = 0; r < 4; ++r)
        Pk[(mbase + r) * ND + n] = acc[mt][nt][r];
    }
}

// Sum KS partials, add beta on row 128, write split bf16 (full width).
__global__ __launch_bounds__(256) void reduce_step(
    const float* __restrict__ P, const float* __restrict__ beta,
    unsigned short* __restrict__ Ohi, unsigned short* __restrict__ Olo) {
  int t = blockIdx.x * 256 + threadIdx.x;   // 288*256 = 73728 = MT*ND/4
  int m = t >> 9;
  int n = (t & 511) * 4;
  int idx = m * ND + n;
  const int stride = MT * ND;
  float v0 = 0.f, v1 = 0.f, v2 = 0.f, v3 = 0.f;
#pragma unroll
  for (int c = 0; c < KS; ++c) {
    float4 s = *(const float4*)(P + c * stride + idx);
    v0 += s.x; v1 += s.y; v2 += s.z; v3 += s.w;
  }
  if (m == 128) {
    float4 b4 = *(const float4*)(beta + n);
    v0 += b4.x; v1 += b4.y; v2 += b4.z; v3 += b4.w;
  }
  union { unsigned short u[4]; uint2 d; } h, l;
  float vv[4] = {v0, v1, v2, v3};
#pragma unroll
  for (int i = 0; i < 4; ++i) {
    unsigned short hh = f2bf(vv[i]);
    h.u[i] = hh;
    l.u[i] = f2bf(vv[i] - bf2f(hh));
  }
  *(uint2*)(Ohi + idx) = h.d;
  *(uint2*)(Olo + idx) = l.d;
}

// ---------------------------------------------------------------------------
// Tail (3 wide kernels, fp32-exact S path):
//   extract_Sc: St[d][e] = sum_c P[c][d][1920+e]  (coalesced both sides);
//               c[e] = sum_c P[c][128][1920+e] + beta[1920+e]
//   tail_T1g:   T1[e,ic] = sum_d St[d][e]*Wpre[d,ic];  g[e] = c[e]+St[:,e]·bpre
//   tail_Weff:  Weff[o,ic] = sum_e Wpost[o,e]*T1[e,ic] -> split bf16;
//               beff[o] = bpost[o] + Wpost[o,:]·g
// ---------------------------------------------------------------------------
__global__ __launch_bounds__(256) void extract_Sc(
    const float* __restrict__ P, const float* __restrict__ beta,
    float* __restrict__ St, float* __restrict__ gv) {
  int t = blockIdx.x * 256 + threadIdx.x;
  const int PSTR = MT * ND;
  if (t < 16384) {
    int d = t >> 7, e = t & 127;
    float v = 0.f;
#pragma unroll
    for (int c = 0; c < KS; ++c) v += P[c * PSTR + d * ND + 1920 + e];
    St[t] = v;                                   // St[d][e]
  } else if (t < 16512) {
    int e = t - 16384;
    float v = beta[1920 + e];
#pragma unroll
    for (int c = 0; c < KS; ++c) v += P[c * PSTR + 128 * ND + 1920 + e];
    gv[e] = v;
  }
}

__global__ __launch_bounds__(256) void tail_T1g(
    const float* __restrict__ St, const float* __restrict__ Wpre,
    const float* __restrict__ bpre, float* __restrict__ T1,
    float* __restrict__ gv) {
  int t = blockIdx.x * 256 + threadIdx.x;
  if (t < 65536) {
    int e = t >> 9, ic = t & 511;
    float s = 0.f;
    for (int d = 0; d < 128; ++d) s += St[d * 128 + e] * Wpre[d * 512 + ic];
    T1[t] = s;
  } else if (t < 65664) {
    int e = t - 65536;
    float s = gv[e];
    for (int d = 0; d < 128; ++d) s += St[d * 128 + e] * bpre[d];
    gv[e] = s;                                   // only this thread touches e
  }
}

__global__ __launch_bounds__(256) void tail_Weff(
    const float* __restrict__ Wpost, const float* __restrict__ T1,
    const float* __restrict__ gv, const float* __restrict__ bpost,
    unsigned short* __restrict__ Whi, unsigned short* __restrict__ Wlo,
    float* __restrict__ beff) {
  int t = blockIdx.x * 256 + threadIdx.x;
  if (t < 262144) {
    int o = t >> 9, ic = t & 511;
    float s = 0.f;
    for (int e = 0; e < 128; ++e) s += Wpost[o * 128 + e] * T1[e * 512 + ic];
    unsigned short h = f2bf(s);
    Whi[t] = h;
    Wlo[t] = f2bf(s - bf2f(h));
  } else if (t < 262656) {
    int o = t - 262144;
    float s = bpost[o];
    for (int e = 0; e < 128; ++e) s += Wpost[o * 128 + e] * gv[e];
    beff[o] = s;
  }
}

// ---------------------------------------------------------------------------
// out[4096,512] = inp @ Weff^T + beff. M=4096,N=512,K=512, split bf16.
// Block tile 64(M) x 128(N): grid (64,4), 4 waves; wave w owns n-cols [32w,32w+32).
// ---------------------------------------------------------------------------
__global__ __launch_bounds__(256) void final_gemm(
    const unsigned short* __restrict__ Ihi, const unsigned short* __restrict__ Ilo,
    const unsigned short* __restrict__ Whi, const unsigned short* __restrict__ Wlo,
    const float* __restrict__ beff, float* __restrict__ out) {
  __shared__ __align__(16) unsigned short Is_hi[64][40], Is_lo[64][40];
  __shared__ __align__(16) unsigned short Ws_hi[128][40], Ws_lo[128][40];
  const int t = threadIdx.x;
  const int mb = blockIdx.x, nb = blockIdx.y;
  const int w = t >> 6, lane = t & 63;
  const int r16 = lane & 15, q = lane >> 4;

  f32x4 acc[4][2];
#pragma unroll
  for (int x = 0; x < 4; ++x)
#pragma unroll
    for (int b = 0; b < 2; ++b) acc[x][b] = (f32x4){0.f, 0.f, 0.f, 0.f};

  for (int kc = 0; kc < 16; ++kc) {
    const int k0 = kc * 32;
#pragma unroll
    for (int rpt = 0; rpt < 6; ++rpt) {
      int slot = t + rpt * 256;
      if (slot < 512) {
        int arr = slot >> 8, s = slot & 255;
        int row = s >> 2, off = (s & 3) * 8;
        const unsigned short* src = arr ? Ilo : Ihi;
        unsigned short* dst = arr ? &Is_lo[row][off] : &Is_hi[row][off];
        *(uint4*)dst = *(const uint4*)(src + (mb * 64 + row) * 512 + k0 + off);
      } else {
        int s = slot - 512;
        int arr = s >> 9, s2 = s & 511;
        int row = s2 >> 2, off = (s2 & 3) * 8;
        const unsigned short* src = arr ? Wlo : Whi;
        unsigned short* dst = arr ? &Ws_lo[row][off] : &Ws_hi[row][off];
        *(uint4*)dst = *(const uint4*)(src + (nb * 128 + row) * 512 + k0 + off);
      }
    }
    __syncthreads();

    bf16x8 bh0 = __builtin_bit_cast(bf16x8, *(const uint4*)&Ws_hi[w * 32 + r16][q * 8]);
    bf16x8 bl0 = __builtin_bit_cast(bf16x8, *(const uint4*)&Ws_lo[w * 32 + r16][q * 8]);
    bf16x8 bh1 = __builtin_bit_cast(bf16x8, *(const uint4*)&Ws_hi[w * 32 + 16 + r16][q * 8]);
    bf16x8 bl1 = __builtin_bit_cast(bf16x8, *(const uint4*)&Ws_lo[w * 32 + 16 + r16][q * 8]);
#pragma unroll
    for (int mt = 0; mt < 4; ++mt) {
      bf16x8 ah = __builtin_bit_cast(bf16x8, *(const uint4*)&Is_hi[mt * 16 + r16][q * 8]);
      bf16x8 al = __builtin_bit_cast(bf16x8, *(const uint4*)&Is_lo[mt * 16 + r16][q * 8]);
      acc[mt][0] = mfma16(ah, bh0, acc[mt][0]);
      acc[mt][0] = mfma16(al, bh0, acc[mt][0]);
      acc[mt][0] = mfma16(ah, bl0, acc[mt][0]);
      acc[mt][1] = mfma16(ah, bh1, acc[mt][1]);
      acc[mt][1] = mfma16(al, bh1, acc[mt][1]);
      acc[mt][1] = mfma16(ah, bl1, acc[mt][1]);
    }
    __syncthreads();
  }

#pragma unroll
  for (int mt = 0; mt < 4; ++mt)
#pragma unroll
    for (int nt = 0; nt < 2; ++nt) {
      int n = nb * 128 + w * 32 + nt * 16 + r16;
      float bv = beff[n];
#pragma unroll
      for (int r = 0; r < 4; ++r) {
        int m = mb * 64 + mt * 16 + q * 4 + r;
        out[m * 512 + n] = acc[mt][nt][r] + bv;
      }
    }
}

extern "C" void kernel_launch(void* const* d_in, const int* in_sizes, int n_in,
                              void* d_out, int out_size, void* d_ws, size_t ws_size,
                              hipStream_t stream) {
  const float* inp   = (const float*)d_in[0];
  const float* Wpre  = (const float*)d_in[1];
  const float* bpre  = (const float*)d_in[2];
  const float* W     = (const float*)d_in[3];
  const float* bl    = (const float*)d_in[4];
  const float* life  = (const float*)d_in[5];
  const float* Wpost = (const float*)d_in[6];
  const float* bpost = (const float*)d_in[7];
  float* out = (float*)d_out;

  char* p = (char*)d_ws;
  auto alloc = [&](size_t bytes) {
    char* r = p;
    p += (bytes + 255) & ~(size_t)255;
    return r;
  };
  unsigned short* Ahi  = (unsigned short*)alloc((size_t)ND * ND * 2);
  unsigned short* Alo  = (unsigned short*)alloc((size_t)ND * ND * 2);
  unsigned short* QAhi = (unsigned short*)alloc((size_t)MT * ND * 2);
  unsigned short* QAlo = (unsigned short*)alloc((size_t)MT * ND * 2);
  unsigned short* QBhi = (unsigned short*)alloc((size_t)MT * ND * 2);
  unsigned short* QBlo = (unsigned short*)alloc((size_t)MT * ND * 2);
  float* beta = (float*)alloc(ND * 4);
  float* P    = (float*)alloc((size_t)KS * MT * ND * 4);
  float* St   = (float*)alloc(128 * 128 * 4);
  float* gv   = (float*)alloc(128 * 4);
  float* T1   = (float*)alloc(128 * 512 * 4);
  float* beff = (float*)alloc(512 * 4);
  unsigned short* Whi = (unsigned short*)alloc(512 * 512 * 2);
  unsigned short* Wlo = (unsigned short*)alloc(512 * 512 * 2);
  unsigned short* Ihi = (unsigned short*)alloc((size_t)4096 * 512 * 2);
  unsigned short* Ilo = (unsigned short*)alloc((size_t)4096 * 512 * 2);

  build_all<<<1024, 256, 0, stream>>>(W, life, bl, inp, Ahi, Alo, QAhi, QAlo,
                                      beta, Ihi, Ilo);

  // steps t=2..10: 8 full multiplies + 1 restricted to n in [1920,2048)
  const unsigned short *qh = QAhi, *ql = QAlo;
  unsigned short *oh = QBhi, *ol = QBlo;
  for (int i = 1; i <= 9; ++i) {
    if (i < 9) {
      step_kernel<<<dim3(64, KS), 192, 0, stream>>>(Ahi, Alo, qh, ql, P, 0);
      reduce_step<<<288, 256, 0, stream>>>(P, beta, oh, ol);
      const unsigned short* th = qh; qh = oh; oh = (unsigned short*)th;
      const unsigned short* tl = ql; ql = ol; ol = (unsigned short*)tl;
    } else {
      step_kernel<<<dim3(4, KS), 192, 0, stream>>>(Ahi, Alo, qh, ql, P, 60);
    }
  }

  extract_Sc<<<65, 256, 0, stream>>>(P, beta, St, gv);
  tail_T1g<<<257, 256, 0, stream>>>(St, Wpre, bpre, T1, gv);
  tail_Weff<<<1026, 256, 0, stream>>>(Wpost, T1, gv, bpost, Whi, Wlo, beff);
  final_gemm<<<dim3(64, 4), 256, 0, stream>>>(Ihi, Ilo, Whi, Wlo, beff, out);
}